// Round 5
// baseline (102.880 us; speedup 1.0000x reference)
//
#include <hip/hip_runtime.h>
#include <math.h>

#define BB  16
#define TT  12
#define T2C 10
#define NN  300
#define DD  64
#define M3  900   // 3*NN
#define NW  (BB*T2C)

typedef _Float16 f16;
typedef __attribute__((ext_vector_type(8)))  _Float16 f16x8;
typedef __attribute__((ext_vector_type(16))) float    f32x16;

#define KS  72    // k_U fp16 row stride (144 B)
#define KSM 136   // k_pm fp16 m-stride (128 rows + 8 pad)

static __device__ inline unsigned pk2(f16 a, f16 b) {
    union { f16 h[2]; unsigned u; } x; x.h[0] = a; x.h[1] = b; return x.u;
}

// ---------------------------------------------------------------------------
// k_pm v3 (r3-verified, unchanged): one block per (b,t), 512 threads, 3
// epochs of 128 rows with register prefetch; transposed sspart row-norm
// reduce; 8-wave MFMA (ci,di,kh) with one-shot kh reduce -> Mt fp32.
// blk == 192: sigw + w1/w2 -> fp16 MFMA A-fragment order.
// ---------------------------------------------------------------------------
__global__ __launch_bounds__(512) void k_pm(const float* __restrict__ feat,
                                            const float* __restrict__ weights,
                                            const float* __restrict__ w1,
                                            const float* __restrict__ w2,
                                            float* __restrict__ sigw,
                                            float* __restrict__ invn,
                                            float* __restrict__ tsum,
                                            f16* __restrict__ w1f,
                                            f16* __restrict__ w2f,
                                            float* __restrict__ Mt) {
    int blk = blockIdx.x;
    int tid = threadIdx.x;

    if (blk == BB * TT) {
        if (tid < 64) sigw[tid] = 1.0f / (1.0f + expf(-weights[tid]));
        for (int p = tid; p < 1024; p += 512) {
            int lane = p & 63, s = p >> 6;
            int mat = s >> 3, loc = s & 7, ct = loc >> 2, ksv = loc & 3;
            int hcol = ct * 32 + (lane & 31);
            const float* w = mat ? w2 : w1;
            f16* dst = (mat ? w2f : w1f) + ((size_t)loc * 64 + lane) * 8;
            f16x8 v;
            #pragma unroll
            for (int j = 0; j < 8; j++) {
                int d = ksv * 16 + 8 * (lane >> 5) + j;
                v[j] = (f16)w[d * DD + hcol];
            }
            *(f16x8*)dst = v;
        }
        return;
    }

    __shared__ union __align__(16) {
        struct { f16 Kti[64 * KSM]; f16 Vtt[64 * KSM]; } s;   // 34816 B
        struct { float Mw[64 * 68]; float tspp[64 * 64]; } r; // 33792 B
    } SH;
    __shared__ float sspartT[8][128];   // [wv][row] row-norm partials

    int bt = blk;
    int row0 = bt * NN;
    int wv = tid >> 6, lane = tid & 63;
    int l31 = lane & 31, lh = lane >> 5;
    int ci = wv & 1, di = (wv >> 1) & 1, kh = wv >> 2;
    int mr = (tid & 63) * 2;           // staging m-pair 0..126
    int cb = (tid >> 6) * 8;           // staging 8-col block

    float sg[8];
    {
        float4 wv0 = *(const float4*)(weights + cb);
        float4 wv1 = *(const float4*)(weights + cb + 4);
        sg[0] = 1.f/(1.f+expf(-wv0.x)); sg[1] = 1.f/(1.f+expf(-wv0.y));
        sg[2] = 1.f/(1.f+expf(-wv0.z)); sg[3] = 1.f/(1.f+expf(-wv0.w));
        sg[4] = 1.f/(1.f+expf(-wv1.x)); sg[5] = 1.f/(1.f+expf(-wv1.y));
        sg[6] = 1.f/(1.f+expf(-wv1.z)); sg[7] = 1.f/(1.f+expf(-wv1.w));
    }

    float tacc[8];
    #pragma unroll
    for (int i = 0; i < 8; i++) tacc[i] = 0.f;
    f32x16 acc;
    #pragma unroll
    for (int i = 0; i < 16; i++) acc[i] = 0.f;

#define LOADEP(EP, A, B) do { \
        int M0_ = (EP) * 128 + mr; \
        int g0_ = row0 + ((M0_ < NN) ? M0_ : 0); \
        int g1_ = row0 + ((M0_ + 1 < NN) ? (M0_ + 1) : 0); \
        float4 a0_ = *(const float4*)(feat + (size_t)g0_ * DD + cb); \
        float4 a1_ = *(const float4*)(feat + (size_t)g0_ * DD + cb + 4); \
        float4 b0_ = *(const float4*)(feat + (size_t)g1_ * DD + cb); \
        float4 b1_ = *(const float4*)(feat + (size_t)g1_ * DD + cb + 4); \
        A[0]=a0_.x; A[1]=a0_.y; A[2]=a0_.z; A[3]=a0_.w; \
        A[4]=a1_.x; A[5]=a1_.y; A[6]=a1_.z; A[7]=a1_.w; \
        B[0]=b0_.x; B[1]=b0_.y; B[2]=b0_.z; B[3]=b0_.w; \
        B[4]=b1_.x; B[5]=b1_.y; B[6]=b1_.z; B[7]=b1_.w; \
    } while (0)

    float a_cur[8], b_cur[8];
    LOADEP(0, a_cur, b_cur);

    #pragma unroll
    for (int ep = 0; ep < 3; ep++) {
        int M0 = ep * 128 + mr;
        bool ok0 = M0 < NN, ok1 = (M0 + 1) < NN;   // NN even, M0 even -> ok0==ok1

        float ss0 = 0.f, ss1 = 0.f;
        #pragma unroll
        for (int i = 0; i < 8; i++) {
            float xa = a_cur[i] * sg[i], xb = b_cur[i] * sg[i];
            ss0 += xa * xa; ss1 += xb * xb;
        }
        sspartT[wv][mr] = ss0;
        sspartT[wv][mr + 1] = ss1;

        float a_nxt[8], b_nxt[8];
        if (ep < 2) LOADEP(ep + 1, a_nxt, b_nxt);   // prefetch under barrier chain

        __syncthreads();     // A: sspart ready; prev-epoch MFMA reads drained
        float2 p0 = *(const float2*)&sspartT[0][mr];
        float s0 = p0.x, s1 = p0.y;
        #pragma unroll
        for (int j = 1; j < 8; j++) {
            float2 pj = *(const float2*)&sspartT[j][mr];
            s0 += pj.x; s1 += pj.y;
        }
        float in0 = 1.0f / fmaxf(sqrtf(s0), 1e-12f);
        float in1 = 1.0f / fmaxf(sqrtf(s1), 1e-12f);
        if (wv == 0 && ok0) *(float2*)&invn[row0 + M0] = make_float2(in0, in1);
        float i0 = ok0 ? in0 : 0.f;
        float i1 = ok1 ? in1 : 0.f;
        #pragma unroll
        for (int i = 0; i < 8; i++) {
            *(unsigned*)&SH.s.Kti[(cb + i) * KSM + mr] =
                pk2((f16)(a_cur[i] * i0), (f16)(b_cur[i] * i1));
            *(unsigned*)&SH.s.Vtt[(cb + i) * KSM + mr] =
                pk2((f16)a_cur[i], (f16)b_cur[i]);
            tacc[i] += a_cur[i] * i0 + b_cur[i] * i1;
        }
        __syncthreads();     // B: pack ready
        #pragma unroll
        for (int ks = 0; ks < 4; ks++) {
            f16x8 af = *(const f16x8*)&SH.s.Kti[(ci*32+l31)*KSM + kh*64 + ks*16 + 8*lh];
            f16x8 bf = *(const f16x8*)&SH.s.Vtt[(di*32+l31)*KSM + kh*64 + ks*16 + 8*lh];
            acc = __builtin_amdgcn_mfma_f32_32x32x16_f16(af, bf, acc, 0, 0, 0);
        }
        if (ep < 2) {
            #pragma unroll
            for (int i = 0; i < 8; i++) { a_cur[i] = a_nxt[i]; b_cur[i] = b_nxt[i]; }
        }
    }
#undef LOADEP

    // ---- tail: reduce kh partials -> Mt fp32; tacc -> tsum ----
    __syncthreads();                                   // last MFMA reads done
    if (kh == 1) {
        #pragma unroll
        for (int g = 0; g < 4; g++)
            *(float4*)&SH.r.Mw[(di*32+l31)*68 + ci*32 + 8*g + 4*lh] =
                make_float4(acc[4*g+0], acc[4*g+1], acc[4*g+2], acc[4*g+3]);
    }
    #pragma unroll
    for (int i = 0; i < 8; i++) SH.r.tspp[(tid & 63) * 64 + cb + i] = tacc[i] * sg[i];
    __syncthreads();
    if (kh == 0) {
        float* mb = Mt + (size_t)bt * 4096;
        #pragma unroll
        for (int g = 0; g < 4; g++) {
            float4 m = *(const float4*)&SH.r.Mw[(di*32+l31)*68 + ci*32 + 8*g + 4*lh];
            *(float4*)&mb[(di * 32 + l31) * 64 + ci * 32 + 8 * g + 4 * lh] =
                make_float4(acc[4*g+0] + m.x, acc[4*g+1] + m.y,
                            acc[4*g+2] + m.z, acc[4*g+3] + m.w);
        }
    }
    if (tid < 64) {
        float s = 0.f;
        #pragma unroll 8
        for (int j = 0; j < 64; j++) s += SH.r.tspp[j * 64 + tid];
        tsum[(size_t)bt * 64 + tid] = s;
    }
}

// ---------------------------------------------------------------------------
// k_U v3: barrier chain 6 -> 4.
//  - ksum computed per-thread from tsum global (same per-element order) ->
//    barrier #1 and the tid<64 entry serialization removed.
//  - row-max fused into phase A: lane pair (lane, lane^32) covers the whole
//    Ol row; lane-local max + shfl_xor(32) (max is order-exact). Removes the
//    separate max pass, barrier #4, and scls; isls visibility covered by
//    the existing #5/#6 barriers.
// All reduction orders preserved -> bit-identical output.
// ---------------------------------------------------------------------------
__global__ __launch_bounds__(256) void k_U(const float* __restrict__ feat,
                                           const float* __restrict__ sigw,
                                           const float* __restrict__ invn,
                                           const float* __restrict__ tsum,
                                           const float* __restrict__ Mt,
                                           const f16* __restrict__ w1f,
                                           const f16* __restrict__ w2f,
                                           const float* __restrict__ b1,
                                           const float* __restrict__ b2,
                                           const float* __restrict__ gamma,
                                           const float* __restrict__ beta,
                                           float* __restrict__ out) {
    __shared__ union __align__(16) {
        f16 Mh[64 * KS];
        f16 Hl[64 * KS];
    } MH;
    __shared__ float Ol[64 * 68];
    __shared__ float degs[64];
    __shared__ float isls[64];

    int blk = blockIdx.x;
    int wdw = blk % NW;            // XCD swizzle
    int rb  = blk / NW;
    int t2 = wdw % T2C, b = wdw / T2C;
    int n0 = rb * 64;
    int qrow0 = (b * TT + t2 + 2) * NN;
    int tid = threadIdx.x;
    int wv = tid >> 6, lane = tid & 63;
    int l31 = lane & 31, lh = lane >> 5;
    int nt = wv & 1;
    int dt = wv >> 1;
    int ct = wv & 1, rt = wv >> 1;
    int r = tid >> 2, q = tid & 3, c0 = q * 16;
    int lq = lane & ~3;            // quad base lane (within wave)

    f16x8 w1a[4], w2a[4];
    #pragma unroll
    for (int ks = 0; ks < 4; ks++) {
        w1a[ks] = *(const f16x8*)(w1f + ((size_t)(ct * 4 + ks) * 64 + lane) * 8);
        w2a[ks] = *(const f16x8*)(w2f + ((size_t)(ct * 4 + ks) * 64 + lane) * 8);
    }

    // per-thread ksum for this thread's 16 columns (order == tp[0]+tp[64]+tp[128])
    float kv[16];
    {
        const float* tp = tsum + (size_t)(b * TT + t2) * 64;
        #pragma unroll
        for (int i = 0; i < 4; i++) {
            float4 k0 = *(const float4*)(tp + c0 + 4 * i);
            float4 k1 = *(const float4*)(tp + 64 + c0 + 4 * i);
            float4 k2 = *(const float4*)(tp + 128 + c0 + 4 * i);
            kv[4*i+0] = k0.x + k1.x + k2.x; kv[4*i+1] = k0.y + k1.y + k2.y;
            kv[4*i+2] = k0.z + k1.z + k2.z; kv[4*i+3] = k0.w + k1.w + k2.w;
        }
    }

    // Q'' B-frags: feat_q * sigw^2 * invn_q
    f16x8 qf[4];
    {
        int nloc = n0 + nt * 32 + l31;
        bool ok = nloc < NN;
        int gr = qrow0 + (ok ? nloc : 0);
        float in = ok ? invn[gr] : 0.f;
        #pragma unroll
        for (int ks = 0; ks < 4; ks++) {
            int cc = ks * 16 + 8 * lh;
            float4 f0 = *(const float4*)(feat + (size_t)gr * DD + cc);
            float4 f1 = *(const float4*)(feat + (size_t)gr * DD + cc + 4);
            float4 s0 = *(const float4*)(sigw + cc);
            float4 s1 = *(const float4*)(sigw + cc + 4);
            f16x8 qv;
            qv[0] = (f16)(f0.x * s0.x * s0.x * in); qv[1] = (f16)(f0.y * s0.y * s0.y * in);
            qv[2] = (f16)(f0.z * s0.z * s0.z * in); qv[3] = (f16)(f0.w * s0.w * s0.w * in);
            qv[4] = (f16)(f1.x * s1.x * s1.x * in); qv[5] = (f16)(f1.y * s1.y * s1.y * in);
            qv[6] = (f16)(f1.z * s1.z * s1.z * in); qv[7] = (f16)(f1.w * s1.w * s1.w * in);
            qf[ks] = qv;
        }
    }

    // M_w = sum of 3 Mt slabs (fp32)
    float ms[16];
    {
        const float* mtb = Mt + (size_t)(b * TT + t2) * 4096 + r * 64 + c0;
        #pragma unroll
        for (int i = 0; i < 4; i++) {
            float4 m0 = *(const float4*)(mtb + 4 * i);
            float4 m1 = *(const float4*)(mtb + 4096 + 4 * i);
            float4 m2 = *(const float4*)(mtb + 8192 + 4 * i);
            ms[4*i+0] = m0.x + m1.x + m2.x; ms[4*i+1] = m0.y + m1.y + m2.y;
            ms[4*i+2] = m0.z + m1.z + m2.z; ms[4*i+3] = m0.w + m1.w + m2.w;
        }
    }

    // residual feat rows + invq
    int n = n0 + r;
    int nc = (n < NN) ? n : (NN - 1);
    size_t frow = ((size_t)qrow0 + nc) * DD;
    float fv[16];
    #pragma unroll
    for (int i = 0; i < 4; i++) {
        float4 f = *(const float4*)(feat + frow + c0 + 4 * i);
        fv[4*i+0] = f.x; fv[4*i+1] = f.y; fv[4*i+2] = f.z; fv[4*i+3] = f.w;
    }
    float invq = invn[qrow0 + nc];

    // deg: per-thread partial -> ordered quad shuffle sum -> degs[r]
    {
        float p = 0.f;
        #pragma unroll
        for (int i = 0; i < 4; i++) {
            float4 s = *(const float4*)(sigw + c0 + 4 * i);
            p += fv[4*i+0] * s.x * kv[4*i+0] + fv[4*i+1] * s.y * kv[4*i+1]
               + fv[4*i+2] * s.z * kv[4*i+2] + fv[4*i+3] * s.w * kv[4*i+3];
        }
        p *= invq;
        float dsum = __shfl(p, lq + 0) + __shfl(p, lq + 1)
                   + __shfl(p, lq + 2) + __shfl(p, lq + 3);
        if (q == 0) degs[r] = dsum;
    }

    // Mh fp16 [d][c]
    #pragma unroll
    for (int hhalf = 0; hhalf < 2; hhalf++) {
        f16x8 v;
        #pragma unroll
        for (int j = 0; j < 8; j++) v[j] = (f16)ms[8 * hhalf + j];
        *(f16x8*)&MH.Mh[r * KS + c0 + 8 * hhalf] = v;
    }
    __syncthreads();   // #2: Mh + degs ready

    // U^T tile: D[d][n] = sum_c M(c,d) Q''(n,c)
    f32x16 ua;
    #pragma unroll
    for (int i = 0; i < 16; i++) ua[i] = 0.f;
    #pragma unroll
    for (int ks = 0; ks < 4; ks++) {
        f16x8 af = *(const f16x8*)&MH.Mh[(dt * 32 + l31) * KS + ks * 16 + 8 * lh];
        ua = __builtin_amdgcn_mfma_f32_32x32x16_f16(af, qf[ks], ua, 0, 0, 0);
    }

    // Ol[n][d] = U * dinv
    {
        int nl = nt * 32 + l31;
        float dg = degs[nl];
        float dinv = (dg == 0.f) ? 0.f : 1.f / dg;
        #pragma unroll
        for (int g = 0; g < 4; g++)
            *(float4*)&Ol[nl * 68 + dt * 32 + 8 * g + 4 * lh] =
                make_float4(ua[4*g+0] * dinv, ua[4*g+1] * dinv,
                            ua[4*g+2] * dinv, ua[4*g+3] * dinv);
    }
    __syncthreads();   // #3: Ol ready

    // phase A: hoist Ol row slice, inline row-max (lane + lane^32 covers the
    // full row; max is order-exact), pow2 scale, then MFMA
    float pv[32];
    {
        const float* orow = &Ol[(rt * 32 + l31) * 68];
        #pragma unroll
        for (int ks = 0; ks < 4; ks++) {
            float4 pa = *(const float4*)(orow + ks * 16 + 8 * lh);
            float4 pb = *(const float4*)(orow + ks * 16 + 8 * lh + 4);
            pv[8*ks+0] = pa.x; pv[8*ks+1] = pa.y; pv[8*ks+2] = pa.z; pv[8*ks+3] = pa.w;
            pv[8*ks+4] = pb.x; pv[8*ks+5] = pb.y; pv[8*ks+6] = pb.z; pv[8*ks+7] = pb.w;
        }
    }
    float sclrow, isrow;
    {
        float mx = 0.f;
        #pragma unroll
        for (int i = 0; i < 32; i++) mx = fmaxf(mx, fabsf(pv[i]));
        mx = fmaxf(mx, __shfl_xor(mx, 32));
        int e = 0;
        frexpf(mx, &e);
        sclrow = (mx > 1.f) ? exp2f((float)-e) : 1.f;
        isrow  = (mx > 1.f) ? exp2f((float)e) : 1.f;
        isls[rt * 32 + l31] = isrow;   // duplicate identical writes, benign
    }

    f32x16 hc;
    #pragma unroll
    for (int i = 0; i < 16; i++) hc[i] = 0.f;
    #pragma unroll
    for (int ks = 0; ks < 4; ks++) {
        f16x8 bf;
        #pragma unroll
        for (int j = 0; j < 8; j++) bf[j] = (f16)(pv[8*ks+j] * sclrow);
        hc = __builtin_amdgcn_mfma_f32_32x32x16_f16(w1a[ks], bf, hc, 0, 0, 0);
    }
    #pragma unroll
    for (int g = 0; g < 4; g++) {
        union { f16 h[4]; uint2 u; } p;
        #pragma unroll
        for (int i = 0; i < 4; i++) {
            int hcol = ct * 32 + 8 * g + 4 * lh + i;
            p.h[i] = (f16)fmaxf(hc[4 * g + i] + sclrow * b1[hcol], 0.f);
        }
        *(uint2*)&MH.Hl[(rt * 32 + l31) * KS + ct * 32 + 8 * g + 4 * lh] = p.u;
    }
    __syncthreads();   // #5: Hl + isls ready (all phase-A Ol reads done)

    // phase B: o_s^T = w2^T . h_s^T ; overwrite Ol (safe after #5)
    f32x16 oc;
    #pragma unroll
    for (int i = 0; i < 16; i++) oc[i] = 0.f;
    #pragma unroll
    for (int ks = 0; ks < 4; ks++) {
        f16x8 bf = *(const f16x8*)&MH.Hl[(rt * 32 + l31) * KS + ks * 16 + 8 * lh];
        oc = __builtin_amdgcn_mfma_f32_32x32x16_f16(w2a[ks], bf, oc, 0, 0, 0);
    }
    #pragma unroll
    for (int g = 0; g < 4; g++) {
        float4 o4 = make_float4(oc[4*g+0], oc[4*g+1], oc[4*g+2], oc[4*g+3]);
        *(float4*)&Ol[(rt * 32 + l31) * 68 + ct * 32 + 8 * g + 4 * lh] = o4;
    }
    __syncthreads();   // #6: Ol(=o_s) ready

    // epilogue: s = o_s/s_n + b2 + residual; LayerNorm via ordered quad
    // shuffles; guarded store
    float is = isls[r];
    float v[16];
    float sum = 0.f;
    #pragma unroll
    for (int i = 0; i < 16; i++) {
        int c = c0 + i;
        float x = Ol[r * 68 + c] * is + b2[c] + fv[i];
        v[i] = x; sum += x;
    }
    float musum = __shfl(sum, lq + 0) + __shfl(sum, lq + 1)
                + __shfl(sum, lq + 2) + __shfl(sum, lq + 3);
    float mu = musum * (1.f / 64.f);
    float s2 = 0.f;
    #pragma unroll
    for (int i = 0; i < 16; i++) { float d = v[i] - mu; s2 += d * d; }
    float vsum = __shfl(s2, lq + 0) + __shfl(s2, lq + 1)
               + __shfl(s2, lq + 2) + __shfl(s2, lq + 3);
    float var = vsum * (1.f / 64.f);
    float rs = rsqrtf(var + 1e-5f);
    if (n < NN) {
        size_t grow = (size_t)wdw * NN + n;
        #pragma unroll
        for (int i4 = 0; i4 < 4; i4++) {
            int c = c0 + 4 * i4;
            float4 g4 = *(const float4*)(gamma + c);
            float4 be = *(const float4*)(beta + c);
            float4 o4;
            o4.x = (v[4*i4+0] - mu) * rs * g4.x + be.x;
            o4.y = (v[4*i4+1] - mu) * rs * g4.y + be.y;
            o4.z = (v[4*i4+2] - mu) * rs * g4.z + be.z;
            o4.w = (v[4*i4+3] - mu) * rs * g4.w + be.w;
            *(float4*)(out + grow * DD + c) = o4;
        }
    }
}

// ---------------------------------------------------------------------------
extern "C" void kernel_launch(void* const* d_in, const int* in_sizes, int n_in,
                              void* d_out, int out_size, void* d_ws, size_t ws_size,
                              hipStream_t stream) {
    const float* feat    = (const float*)d_in[0];
    const float* weights = (const float*)d_in[1];
    const float* w1      = (const float*)d_in[2];
    const float* b1      = (const float*)d_in[3];
    const float* w2      = (const float*)d_in[4];
    const float* b2      = (const float*)d_in[5];
    const float* gamma   = (const float*)d_in[6];
    const float* beta    = (const float*)d_in[7];
    float* out = (float*)d_out;

    float* sigw = (float*)d_ws;                 // 64
    float* invn = sigw + 64;                    // 57600
    float* tsum = invn + BB * TT * NN;          // 192*64 = 12288
    f16*   w1f  = (f16*)(tsum + BB * TT * DD);  // 4096 f16
    f16*   w2f  = w1f + 4096;                   // 4096 f16
    float* Mt   = (float*)(w2f + 4096);         // 192*4096 floats

    k_pm<<<BB * TT + 1, 512, 0, stream>>>(feat, weights, w1, w2, sigw, invn,
                                          tsum, w1f, w2f, Mt);
    k_U<<<NW * 5, 256, 0, stream>>>(feat, sigw, invn, tsum, Mt, w1f, w2f,
                                    b1, b2, gamma, beta, out);
}